// Round 1
// baseline (1253.825 us; speedup 1.0000x reference)
//
#include <hip/hip_runtime.h>
#include <math.h>

// Problem constants
#define BATCH   8
#define SEQLEN  2048
#define DMODEL  1024
#define NSTATE  1024
#define KFREQ   513        // unique half-spectrum freqs 0..512
#define KF      528        // padded freq count (513 + 15 pad), 2*KF = 1056 = 33*32
#define K2      (2*KF)     // 1056: [0,KF) = real part, [KF,2KF) = imag part
#define BT_ROWS (BATCH*SEQLEN)   // 16384
#define NC      32         // time chunks for parallel scan
#define TC      64         // chunk length; NC*TC == SEQLEN

static_assert(NC * TC == SEQLEN, "chunking must cover SEQLEN");

// ---------------------------------------------------------------------------
// K0: lambda_k = (1 - i w)/(1 + i w),  w = omega_k = Im(FFT(a_full))[k]
// a_full is odd-symmetric => omega[k] = -2 * sum_{j=1..511} p[j-1] sin(2pi j k/1024)
// ---------------------------------------------------------------------------
__global__ __launch_bounds__(1024) void compute_lambda(const float* __restrict__ p,
                                                        float* __restrict__ lam) {
    __shared__ float stab[1024];
    const int tid = threadIdx.x;
    stab[tid] = sinf((float)tid * (6.28318530717958647692f / 1024.0f));
    __syncthreads();
    if (tid < KF) {
        if (tid < KFREQ) {
            float om = 0.0f;
            for (int j = 1; j <= 511; ++j)
                om = fmaf(p[j - 1], stab[(j * tid) & 1023], om);
            om *= -2.0f;
            const float w2 = om * om;
            const float den = 1.0f + w2;
            lam[tid]      = (1.0f - w2) / den;
            lam[KF + tid] = -2.0f * om / den;
        } else {
            lam[tid] = 0.0f;
            lam[KF + tid] = 0.0f;
        }
    }
}

// ---------------------------------------------------------------------------
// Generate trig matrix T[k2][n] (K2 x 1024).
// mode 0 (for B):  rows [0,513): cos(2pi kf n/1024);  rows [KF, KF+513): -sin(...)
// mode 1 (for C):  rows [0,513): (w/N) cos;           rows [KF, KF+513): -(w/N) sin
//                  w = 1 for kf in {0,512}, else 2.
// Integer phase reduction keeps fp32 trig exact-enough at large kf*n.
// ---------------------------------------------------------------------------
__global__ void gen_T(float* __restrict__ T, int mode) {
    const int idx = blockIdx.x * 256 + threadIdx.x;
    if (idx >= K2 * DMODEL) return;
    const int k2 = idx >> 10;
    const int n  = idx & 1023;
    const bool im = (k2 >= KF);
    const int kf = im ? (k2 - KF) : k2;
    float val = 0.0f;
    if (kf < KFREQ) {
        const int m = (kf * n) & 1023;
        const float ang = (float)m * (6.28318530717958647692f / 1024.0f);
        float s, c;
        sincosf(ang, &s, &c);
        float v = im ? -s : c;
        if (mode == 1) {
            const float w = (kf == 0 || kf == 512) ? 1.0f : 2.0f;
            v *= (w / 1024.0f);
        }
        val = v;
    }
    T[idx] = val;
}

// ---------------------------------------------------------------------------
// Generic fp32 tiled GEMM: C[M][N] = sum_k A[M][K] * B
//   BT = true : B stored [N][K] row-major (contract over last dim of both)
//   BT = false: B stored [K][N] row-major
//   EPI: C += Dv[n] * uu[m*N + n]  (only used with N == DMODEL)
// 64x64 tile, BK=16, 256 threads, 4x4 micro-tile per thread.
// ---------------------------------------------------------------------------
template <bool BT, bool EPI>
__global__ __launch_bounds__(256) void gemm_f32(const float* __restrict__ A,
                                                const float* __restrict__ B,
                                                float* __restrict__ C,
                                                int M, int N, int K,
                                                int lda, int ldb, int ldc,
                                                const float* __restrict__ uu,
                                                const float* __restrict__ Dv) {
    __shared__ float As[16][64];
    __shared__ float Bs[16][64];
    const int tid = threadIdx.x;
    const int tx = tid & 15, ty = tid >> 4;
    const int m0 = blockIdx.x * 64, n0 = blockIdx.y * 64;
    float acc[4][4] = {};

    const int lr = tid >> 2;          // 0..63: tile row (A: m, BT-B: n)
    const int lc = (tid & 3) << 2;    // 0,4,8,12: k offset

    for (int k0 = 0; k0 < K; k0 += 16) {
        // stage A tile (64 x 16), transposed into As[k][m]
        {
            float4 va = make_float4(0.f, 0.f, 0.f, 0.f);
            const int am = m0 + lr;
            if (am < M)
                va = *reinterpret_cast<const float4*>(A + (size_t)am * lda + k0 + lc);
            As[lc + 0][lr] = va.x; As[lc + 1][lr] = va.y;
            As[lc + 2][lr] = va.z; As[lc + 3][lr] = va.w;
        }
        if (BT) {
            float4 vb = make_float4(0.f, 0.f, 0.f, 0.f);
            const int bn = n0 + lr;
            if (bn < N)
                vb = *reinterpret_cast<const float4*>(B + (size_t)bn * ldb + k0 + lc);
            Bs[lc + 0][lr] = vb.x; Bs[lc + 1][lr] = vb.y;
            Bs[lc + 2][lr] = vb.z; Bs[lc + 3][lr] = vb.w;
        } else {
            const int bk = tid >> 4;          // 0..15
            const int bn = (tid & 15) << 2;   // 0..60
            float4 vb = make_float4(0.f, 0.f, 0.f, 0.f);
            if (n0 + bn < N)   // N % 4 == 0 so whole float4 is in-bounds
                vb = *reinterpret_cast<const float4*>(B + (size_t)(k0 + bk) * ldb + n0 + bn);
            *reinterpret_cast<float4*>(&Bs[bk][bn]) = vb;
        }
        __syncthreads();
#pragma unroll
        for (int kk = 0; kk < 16; ++kk) {
            const float4 a = *reinterpret_cast<const float4*>(&As[kk][ty << 2]);
            const float4 b = *reinterpret_cast<const float4*>(&Bs[kk][tx << 2]);
            const float av[4] = {a.x, a.y, a.z, a.w};
            const float bv[4] = {b.x, b.y, b.z, b.w};
#pragma unroll
            for (int i = 0; i < 4; ++i)
#pragma unroll
                for (int j = 0; j < 4; ++j)
                    acc[i][j] = fmaf(av[i], bv[j], acc[i][j]);
        }
        __syncthreads();
    }

#pragma unroll
    for (int i = 0; i < 4; ++i) {
        const int m = m0 + (ty << 2) + i;
        if (m >= M) continue;
#pragma unroll
        for (int j = 0; j < 4; ++j) {
            const int n = n0 + (tx << 2) + j;
            if (n >= N) continue;
            float val = acc[i][j];
            if (EPI) val = fmaf(Dv[n], uu[(size_t)m * N + n], val);
            C[(size_t)m * ldc + n] = val;
        }
    }
}

// ---------------------------------------------------------------------------
// Chunked parallel scan over time, in place on UH (layout [b*S][K2]).
// Per (b, kf):  H_t = lambda_kf * H_{t-1} + U_t  (complex; re at kf, im at KF+kf)
// ---------------------------------------------------------------------------
__global__ __launch_bounds__(256) void scan_local(float* __restrict__ UH,
                                                  const float* __restrict__ lam) {
    const int gid = blockIdx.x * 256 + threadIdx.x;
    if (gid >= BATCH * NC * KF) return;
    const int kf = gid % KF;
    const int bc = gid / KF;
    const int c = bc % NC;
    const int b = bc / NC;
    const float lr = lam[kf], li = lam[KF + kf];
    float* base = UH + ((size_t)(b * SEQLEN + c * TC)) * K2 + kf;
    float hr = 0.0f, hi = 0.0f;
    for (int t = 0; t < TC; ++t) {
        const float ur = base[(size_t)t * K2];
        const float ui = base[(size_t)t * K2 + KF];
        const float nr = fmaf(lr, hr, fmaf(-li, hi, ur));
        const float ni = fmaf(lr, hi, fmaf(li, hr, ui));
        base[(size_t)t * K2] = nr;
        base[(size_t)t * K2 + KF] = ni;
        hr = nr; hi = ni;
    }
}

// Sequential carry recurrence over the NC chunks (tiny).
// Ac[gid] stores the carry INTO chunk c (i.e. global end-state of chunk c-1).
__global__ __launch_bounds__(256) void scan_carry(const float* __restrict__ UH,
                                                  const float* __restrict__ lam,
                                                  float* __restrict__ Ac) {
    const int gid = blockIdx.x * 256 + threadIdx.x;
    if (gid >= BATCH * KF) return;
    const int kf = gid % KF;
    const int b = gid / KF;
    const float lr = lam[kf], li = lam[KF + kf];
    // p = lambda^TC via 6 squarings (TC = 64)
    float pr = lr, pi = li;
    for (int s = 0; s < 6; ++s) {
        const float nr = pr * pr - pi * pi;
        const float ni = 2.0f * pr * pi;
        pr = nr; pi = ni;
    }
    float er = 0.0f, ei = 0.0f;
    for (int c = 0; c < NC; ++c) {
        const size_t ai = (size_t)(b * NC + c) * KF + kf;
        Ac[ai] = er;
        Ac[(size_t)BATCH * NC * KF + ai] = ei;
        const size_t gi = ((size_t)(b * SEQLEN + c * TC + TC - 1)) * K2 + kf;
        const float gr = UH[gi];
        const float gi_ = UH[gi + KF];
        const float nr = fmaf(pr, er, fmaf(-pi, ei, gr));
        const float ni = fmaf(pr, ei, fmaf(pi, er, gi_));
        er = nr; ei = ni;
    }
}

// Broadcast carries: H_global[tau] = H_local[tau] + lambda^{tau+1} * carry
__global__ __launch_bounds__(256) void scan_apply(float* __restrict__ UH,
                                                  const float* __restrict__ lam,
                                                  const float* __restrict__ Ac) {
    const int gid = blockIdx.x * 256 + threadIdx.x;
    if (gid >= BATCH * NC * KF) return;
    const int kf = gid % KF;
    const int bc = gid / KF;
    const int c = bc % NC;
    const int b = bc / NC;
    if (c == 0) return;
    const float er = Ac[gid];
    const float ei = Ac[(size_t)BATCH * NC * KF + gid];
    const float lr = lam[kf], li = lam[KF + kf];
    float* base = UH + ((size_t)(b * SEQLEN + c * TC)) * K2 + kf;
    float pr = lr, pi = li;   // lambda^1
    for (int t = 0; t < TC; ++t) {
        const float hr = base[(size_t)t * K2];
        const float hi = base[(size_t)t * K2 + KF];
        base[(size_t)t * K2]      = fmaf(pr, er, fmaf(-pi, ei, hr));
        base[(size_t)t * K2 + KF] = fmaf(pr, ei, fmaf(pi, er, hi));
        const float nr = fmaf(pr, lr, -pi * li);
        const float ni = fmaf(pr, li, pi * lr);
        pr = nr; pi = ni;
    }
}

// ---------------------------------------------------------------------------
extern "C" void kernel_launch(void* const* d_in, const int* in_sizes, int n_in,
                              void* d_out, int out_size, void* d_ws, size_t ws_size,
                              hipStream_t stream) {
    const float* u  = (const float*)d_in[0];  // [B][S][D]
    const float* ap = (const float*)d_in[1];  // [512]
    const float* Bw = (const float*)d_in[2];  // [N][D]
    const float* Cw = (const float*)d_in[3];  // [D][N]
    const float* Dv = (const float*)d_in[4];  // [D]
    float* out = (float*)d_out;               // [B][S][D]

    char* ws = (char*)d_ws;
    const size_t szUH = (size_t)BT_ROWS * K2 * sizeof(float);     // 69.2 MB
    const size_t szW  = (size_t)K2 * DMODEL * sizeof(float);      // 4.3 MB
    float* UH  = (float*)(ws);
    float* W1  = (float*)(ws + szUH);                 // [k2][d]
    float* W2  = (float*)(ws + szUH + szW);           // [d][k2]
    float* T   = (float*)(ws + szUH + 2 * szW);       // [k2][n] (reused)
    float* lam = (float*)(ws + szUH + 3 * szW);       // re[KF], im[KF]
    float* Ac  = (float*)(ws + szUH + 3 * szW + 2 * KF * sizeof(float));

    // 1) eigenvalues
    compute_lambda<<<1, 1024, 0, stream>>>(ap, lam);

    // 2) W1 = T1 @ B_w   (B2 spectrum of B_w)
    gen_T<<<(K2 * DMODEL) / 256, 256, 0, stream>>>(T, 0);
    {
        dim3 g((K2 + 63) / 64, (DMODEL + 63) / 64);
        gemm_f32<false, false><<<g, 256, 0, stream>>>(T, Bw, W1,
            K2, DMODEL, DMODEL, DMODEL, DMODEL, DMODEL, nullptr, nullptr);
    }
    // 3) W2[d][k2] = sum_n C_w[d][n] T2[k2][n]
    gen_T<<<(K2 * DMODEL) / 256, 256, 0, stream>>>(T, 1);
    {
        dim3 g((DMODEL + 63) / 64, (K2 + 63) / 64);
        gemm_f32<true, false><<<g, 256, 0, stream>>>(Cw, T, W2,
            DMODEL, K2, DMODEL, DMODEL, DMODEL, K2, nullptr, nullptr);
    }
    // 4) U[bt][k2] = sum_d u[bt][d] W1[k2][d]
    {
        dim3 g(BT_ROWS / 64, (K2 + 63) / 64);
        gemm_f32<true, false><<<g, 256, 0, stream>>>(u, W1, UH,
            BT_ROWS, K2, DMODEL, DMODEL, DMODEL, K2, nullptr, nullptr);
    }
    // 5) scan over time (in place): local, carry, apply
    scan_local<<<(BATCH * NC * KF + 255) / 256, 256, 0, stream>>>(UH, lam);
    scan_carry<<<(BATCH * KF + 255) / 256, 256, 0, stream>>>(UH, lam, Ac);
    scan_apply<<<(BATCH * NC * KF + 255) / 256, 256, 0, stream>>>(UH, lam, Ac);

    // 6) y[bt][d] = sum_k2 H[bt][k2] W2[d][k2] + D[d]*u[bt][d]
    {
        dim3 g(BT_ROWS / 64, DMODEL / 64);
        gemm_f32<true, true><<<g, 256, 0, stream>>>(UH, W2, out,
            BT_ROWS, DMODEL, K2, K2, K2, DMODEL, u, Dv);
    }
}

// Round 3
// 391.510 us; speedup vs baseline: 3.2025x; 3.2025x over previous
//
#include <hip/hip_runtime.h>
#include <math.h>

// Problem constants
#define BATCH   8
#define SEQLEN  2048
#define DMODEL  1024
#define KFREQ   513        // unique half-spectrum freqs 0..512
#define KF      528        // padded freq count; 2*KF = 1056 = 33*32
#define K2      (2*KF)     // 1056: [0,KF)=real, [KF,2KF)=imag
#define NPAD1   1152       // K2 padded to multiple of 128 for bf16 GEMM N-dim
#define BT_ROWS (BATCH*SEQLEN)   // 16384
#define NC      32         // time chunks for parallel scan
#define TC      64         // chunk length; NC*TC == SEQLEN

static_assert(NC * TC == SEQLEN, "chunking must cover SEQLEN");

typedef __attribute__((ext_vector_type(4))) float f32x4;
typedef __attribute__((ext_vector_type(8))) short bf16x8;   // 8 bf16 in 4 VGPRs
typedef unsigned short ushort_t;

__device__ __forceinline__ ushort_t f2bf(float f) {
    union { float f; unsigned u; } v; v.f = f;
    unsigned r = v.u + 0x7FFFu + ((v.u >> 16) & 1u);   // RNE
    return (ushort_t)(r >> 16);
}

__device__ __forceinline__ void async_cp16(const void* g, void* l) {
    __builtin_amdgcn_global_load_lds(
        (const __attribute__((address_space(1))) void*)g,
        (__attribute__((address_space(3))) void*)l, 16, 0, 0);
}

// ---------------------------------------------------------------------------
// lambda_k = (1 - i w)/(1 + i w),  w = Im(FFT(a_full))[k]
// ---------------------------------------------------------------------------
__global__ __launch_bounds__(1024) void compute_lambda(const float* __restrict__ p,
                                                        float* __restrict__ lam) {
    __shared__ float stab[1024];
    const int tid = threadIdx.x;
    stab[tid] = sinf((float)tid * (6.28318530717958647692f / 1024.0f));
    __syncthreads();
    if (tid < KF) {
        if (tid < KFREQ) {
            float om = 0.0f;
            for (int j = 1; j <= 511; ++j)
                om = fmaf(p[j - 1], stab[(j * tid) & 1023], om);
            om *= -2.0f;
            const float w2 = om * om;
            const float den = 1.0f + w2;
            lam[tid]      = (1.0f - w2) / den;
            lam[KF + tid] = -2.0f * om / den;
        } else {
            lam[tid] = 0.0f;
            lam[KF + tid] = 0.0f;
        }
    }
}

// ---------------------------------------------------------------------------
// Trig matrix T[k2][n] (K2 x 1024); mode 0 for B-spectrum, mode 1 for C.
// ---------------------------------------------------------------------------
__global__ void gen_T(float* __restrict__ T, int mode) {
    const int idx = blockIdx.x * 256 + threadIdx.x;
    if (idx >= K2 * DMODEL) return;
    const int k2 = idx >> 10;
    const int n  = idx & 1023;
    const bool im = (k2 >= KF);
    const int kf = im ? (k2 - KF) : k2;
    float val = 0.0f;
    if (kf < KFREQ) {
        const int m = (kf * n) & 1023;
        const float ang = (float)m * (6.28318530717958647692f / 1024.0f);
        float s, c;
        sincosf(ang, &s, &c);
        float v = im ? -s : c;
        if (mode == 1) {
            const float w = (kf == 0 || kf == 512) ? 1.0f : 2.0f;
            v *= (w / 1024.0f);
        }
        val = v;
    }
    T[idx] = val;
}

// ---------------------------------------------------------------------------
// fp32 tiled GEMM (for the two small weight-precompute GEMMs only).
// ---------------------------------------------------------------------------
template <bool BT>
__global__ __launch_bounds__(256) void gemm_f32(const float* __restrict__ A,
                                                const float* __restrict__ B,
                                                float* __restrict__ C,
                                                int M, int N, int K,
                                                int lda, int ldb, int ldc) {
    __shared__ float As[16][64];
    __shared__ float Bs[16][64];
    const int tid = threadIdx.x;
    const int tx = tid & 15, ty = tid >> 4;
    const int m0 = blockIdx.x * 64, n0 = blockIdx.y * 64;
    float acc[4][4] = {};
    const int lr = tid >> 2;
    const int lc = (tid & 3) << 2;

    for (int k0 = 0; k0 < K; k0 += 16) {
        {
            float4 va = make_float4(0.f, 0.f, 0.f, 0.f);
            const int am = m0 + lr;
            if (am < M)
                va = *reinterpret_cast<const float4*>(A + (size_t)am * lda + k0 + lc);
            As[lc + 0][lr] = va.x; As[lc + 1][lr] = va.y;
            As[lc + 2][lr] = va.z; As[lc + 3][lr] = va.w;
        }
        if (BT) {
            float4 vb = make_float4(0.f, 0.f, 0.f, 0.f);
            const int bn = n0 + lr;
            if (bn < N)
                vb = *reinterpret_cast<const float4*>(B + (size_t)bn * ldb + k0 + lc);
            Bs[lc + 0][lr] = vb.x; Bs[lc + 1][lr] = vb.y;
            Bs[lc + 2][lr] = vb.z; Bs[lc + 3][lr] = vb.w;
        } else {
            const int bk = tid >> 4;
            const int bn = (tid & 15) << 2;
            float4 vb = make_float4(0.f, 0.f, 0.f, 0.f);
            if (n0 + bn < N)
                vb = *reinterpret_cast<const float4*>(B + (size_t)(k0 + bk) * ldb + n0 + bn);
            *reinterpret_cast<float4*>(&Bs[bk][bn]) = vb;
        }
        __syncthreads();
#pragma unroll
        for (int kk = 0; kk < 16; ++kk) {
            const float4 a = *reinterpret_cast<const float4*>(&As[kk][ty << 2]);
            const float4 b = *reinterpret_cast<const float4*>(&Bs[kk][tx << 2]);
            const float av[4] = {a.x, a.y, a.z, a.w};
            const float bv[4] = {b.x, b.y, b.z, b.w};
#pragma unroll
            for (int i = 0; i < 4; ++i)
#pragma unroll
                for (int j = 0; j < 4; ++j)
                    acc[i][j] = fmaf(av[i], bv[j], acc[i][j]);
        }
        __syncthreads();
    }
#pragma unroll
    for (int i = 0; i < 4; ++i) {
        const int m = m0 + (ty << 2) + i;
        if (m >= M) continue;
#pragma unroll
        for (int j = 0; j < 4; ++j) {
            const int n = n0 + (tx << 2) + j;
            if (n >= N) continue;
            C[(size_t)m * ldc + n] = acc[i][j];
        }
    }
}

// ---------------------------------------------------------------------------
// bf16 MFMA GEMM (m97 structure): C[M][ldc](fp32) = A[M][K](bf16) @ B[Npad][K]^T
// 128x128 tile, BK=32, 4 waves, 16x16x32 MFMA, global_load_lds staging.
// EPI: C += Dv[n]*uu[m*DMODEL+n]
// ---------------------------------------------------------------------------
template <bool EPI>
__global__ __launch_bounds__(256) void gemm_bf16(const ushort_t* __restrict__ A,
                                                 const ushort_t* __restrict__ B,
                                                 float* __restrict__ C,
                                                 int M, int Nact, int K, int ldc,
                                                 const float* __restrict__ uu,
                                                 const float* __restrict__ Dv) {
    __shared__ ushort_t As[128 * 32];
    __shared__ ushort_t Bs[128 * 32];
    const int tid  = threadIdx.x;
    const int lane = tid & 63;
    const int w    = tid >> 6;
    const int m0 = blockIdx.x * 128;
    const int n0 = blockIdx.y * 128;
    const int wr = (w >> 1) * 64;
    const int wc = (w & 1) * 64;

    f32x4 acc[4][4] = {};

    // staging geometry: element pos within 128x32 tile, chunk0
    const int pos  = w * 512 + lane * 8;
    const int srow = pos >> 5;           // 0..63
    const int scol = pos & 31;

    const int lr = lane & 15;
    const int lk = (lane >> 4) * 8;

    for (int k0 = 0; k0 < K; k0 += 32) {
        __syncthreads();
        // stage A tile (rows m0..m0+127, cols k0..k0+31)
        async_cp16(A + (size_t)(m0 + srow)      * K + k0 + scol, As + w * 512);
        async_cp16(A + (size_t)(m0 + srow + 64) * K + k0 + scol, As + 2048 + w * 512);
        // stage B tile (rows n0..n0+127)
        async_cp16(B + (size_t)(n0 + srow)      * K + k0 + scol, Bs + w * 512);
        async_cp16(B + (size_t)(n0 + srow + 64) * K + k0 + scol, Bs + 2048 + w * 512);
        __syncthreads();

        bf16x8 fa[4], fb[4];
#pragma unroll
        for (int mi = 0; mi < 4; ++mi)
            fa[mi] = *reinterpret_cast<const bf16x8*>(&As[(wr + mi * 16 + lr) * 32 + lk]);
#pragma unroll
        for (int ni = 0; ni < 4; ++ni)
            fb[ni] = *reinterpret_cast<const bf16x8*>(&Bs[(wc + ni * 16 + lr) * 32 + lk]);
#pragma unroll
        for (int mi = 0; mi < 4; ++mi)
#pragma unroll
            for (int ni = 0; ni < 4; ++ni)
                acc[mi][ni] = __builtin_amdgcn_mfma_f32_16x16x32_bf16(
                    fa[mi], fb[ni], acc[mi][ni], 0, 0, 0);
    }

    const int rbase = (lane >> 4) * 4;
#pragma unroll
    for (int mi = 0; mi < 4; ++mi) {
#pragma unroll
        for (int ni = 0; ni < 4; ++ni) {
            const int col = n0 + wc + ni * 16 + lr;
            if (col >= Nact) continue;
#pragma unroll
            for (int j = 0; j < 4; ++j) {
                const int row = m0 + wr + mi * 16 + rbase + j;
                float v = acc[mi][ni][j];
                if (EPI) v = fmaf(Dv[col], uu[(size_t)row * DMODEL + col], v);
                C[(size_t)row * ldc + col] = v;
            }
        }
    }
}

// ---------------------------------------------------------------------------
// conversions fp32 -> bf16 bits
// ---------------------------------------------------------------------------
__global__ __launch_bounds__(256) void conv_bf16(const float* __restrict__ s,
                                                 ushort_t* __restrict__ d, int n8) {
    const int i = blockIdx.x * 256 + threadIdx.x;
    if (i >= n8) return;
    const float4 a = reinterpret_cast<const float4*>(s)[2 * i];
    const float4 b = reinterpret_cast<const float4*>(s)[2 * i + 1];
    ushort_t o[8] = {f2bf(a.x), f2bf(a.y), f2bf(a.z), f2bf(a.w),
                     f2bf(b.x), f2bf(b.y), f2bf(b.z), f2bf(b.w)};
    reinterpret_cast<bf16x8*>(d)[i] = *reinterpret_cast<bf16x8*>(o);
}

// W1 [K2][1024] fp32 -> W1b [NPAD1][1024] bf16 with zero pad rows
__global__ __launch_bounds__(256) void conv_W1(const float* __restrict__ s,
                                               ushort_t* __restrict__ d) {
    const int i = blockIdx.x * 256 + threadIdx.x;   // 8 elements each
    if (i >= NPAD1 * DMODEL / 8) return;
    const int row = (i * 8) >> 10;
    ushort_t o[8] = {0, 0, 0, 0, 0, 0, 0, 0};
    if (row < K2) {
        const float4 a = reinterpret_cast<const float4*>(s)[2 * i];
        const float4 b = reinterpret_cast<const float4*>(s)[2 * i + 1];
        o[0] = f2bf(a.x); o[1] = f2bf(a.y); o[2] = f2bf(a.z); o[3] = f2bf(a.w);
        o[4] = f2bf(b.x); o[5] = f2bf(b.y); o[6] = f2bf(b.z); o[7] = f2bf(b.w);
    }
    reinterpret_cast<bf16x8*>(d)[i] = *reinterpret_cast<bf16x8*>(o);
}

// ---------------------------------------------------------------------------
// Chunked parallel scan (fp32, in place on UH [bt][K2])
// ---------------------------------------------------------------------------
__global__ __launch_bounds__(256) void scan_local(float* __restrict__ UH,
                                                  const float* __restrict__ lam) {
    const int gid = blockIdx.x * 256 + threadIdx.x;
    if (gid >= BATCH * NC * KF) return;
    const int kf = gid % KF;
    const int bc = gid / KF;
    const int c = bc % NC;
    const int b = bc / NC;
    const float lr = lam[kf], li = lam[KF + kf];
    float* base = UH + ((size_t)(b * SEQLEN + c * TC)) * K2 + kf;
    float hr = 0.0f, hi = 0.0f;
    for (int t = 0; t < TC; ++t) {
        const float ur = base[(size_t)t * K2];
        const float ui = base[(size_t)t * K2 + KF];
        const float nr = fmaf(lr, hr, fmaf(-li, hi, ur));
        const float ni = fmaf(lr, hi, fmaf(li, hr, ui));
        base[(size_t)t * K2] = nr;
        base[(size_t)t * K2 + KF] = ni;
        hr = nr; hi = ni;
    }
}

__global__ __launch_bounds__(256) void scan_carry(const float* __restrict__ UH,
                                                  const float* __restrict__ lam,
                                                  float* __restrict__ Ac) {
    const int gid = blockIdx.x * 256 + threadIdx.x;
    if (gid >= BATCH * KF) return;
    const int kf = gid % KF;
    const int b = gid / KF;
    const float lr = lam[kf], li = lam[KF + kf];
    float pr = lr, pi = li;          // lambda^64 via 6 squarings
    for (int s = 0; s < 6; ++s) {
        const float nr = pr * pr - pi * pi;
        const float ni = 2.0f * pr * pi;
        pr = nr; pi = ni;
    }
    float er = 0.0f, ei = 0.0f;
    for (int c = 0; c < NC; ++c) {
        const size_t ai = (size_t)(b * NC + c) * KF + kf;
        Ac[ai] = er;
        Ac[(size_t)BATCH * NC * KF + ai] = ei;
        const size_t gi = ((size_t)(b * SEQLEN + c * TC + TC - 1)) * K2 + kf;
        const float gr = UH[gi];
        const float gm = UH[gi + KF];
        const float nr = fmaf(pr, er, fmaf(-pi, ei, gr));
        const float ni = fmaf(pr, ei, fmaf(pi, er, gm));
        er = nr; ei = ni;
    }
}

// apply carries AND emit bf16 copy of H (UHb) for the output GEMM
__global__ __launch_bounds__(256) void scan_apply_conv(const float* __restrict__ UH,
                                                       const float* __restrict__ lam,
                                                       const float* __restrict__ Ac,
                                                       ushort_t* __restrict__ UHb) {
    const int gid = blockIdx.x * 256 + threadIdx.x;
    if (gid >= BATCH * NC * KF) return;
    const int kf = gid % KF;
    const int bc = gid / KF;
    const int c = bc % NC;
    const int b = bc / NC;
    const float er = Ac[gid];                                  // 0 for c==0
    const float ei = Ac[(size_t)BATCH * NC * KF + gid];
    const float lr = lam[kf], li = lam[KF + kf];
    const size_t off = ((size_t)(b * SEQLEN + c * TC)) * K2 + kf;
    const float* base = UH + off;
    ushort_t* dst = UHb + off;
    float pr = lr, pi = li;   // lambda^1
    for (int t = 0; t < TC; ++t) {
        const float hr = base[(size_t)t * K2];
        const float hi = base[(size_t)t * K2 + KF];
        const float gr = fmaf(pr, er, fmaf(-pi, ei, hr));
        const float gi = fmaf(pr, ei, fmaf(pi, er, hi));
        dst[(size_t)t * K2]      = f2bf(gr);
        dst[(size_t)t * K2 + KF] = f2bf(gi);
        const float nr = fmaf(pr, lr, -pi * li);
        const float ni = fmaf(pr, li, pi * lr);
        pr = nr; pi = ni;
    }
}

// ---------------------------------------------------------------------------
extern "C" void kernel_launch(void* const* d_in, const int* in_sizes, int n_in,
                              void* d_out, int out_size, void* d_ws, size_t ws_size,
                              hipStream_t stream) {
    const float* u  = (const float*)d_in[0];  // [B][S][D]
    const float* ap = (const float*)d_in[1];  // [512]
    const float* Bw = (const float*)d_in[2];  // [N][D]
    const float* Cw = (const float*)d_in[3];  // [D][N]
    const float* Dv = (const float*)d_in[4];  // [D]
    float* out = (float*)d_out;               // [B][S][D]

    char* ws = (char*)d_ws;
    size_t off = 0;
    auto carve = [&](size_t bytes) { char* p = ws + off; off += (bytes + 255) & ~(size_t)255; return p; };

    float*    UH  = (float*)   carve((size_t)BT_ROWS * K2 * sizeof(float));        // 69.2 MB
    ushort_t* ubX = (ushort_t*)carve((size_t)BT_ROWS * K2 * sizeof(ushort_t));     // 34.6 MB (ub then UHb)
    float*    W1  = (float*)   carve((size_t)K2 * DMODEL * sizeof(float));
    float*    W2  = (float*)   carve((size_t)K2 * DMODEL * sizeof(float));
    float*    T   = (float*)   carve((size_t)K2 * DMODEL * sizeof(float));
    ushort_t* W1b = (ushort_t*)carve((size_t)NPAD1 * DMODEL * sizeof(ushort_t));
    ushort_t* W2b = (ushort_t*)carve((size_t)DMODEL * K2 * sizeof(ushort_t));
    float*    lam = (float*)   carve(2 * KF * sizeof(float));
    float*    Ac  = (float*)   carve((size_t)2 * BATCH * NC * KF * sizeof(float));

    ushort_t* ub  = ubX;   // [BT_ROWS][1024] bf16 (phase 1)
    ushort_t* UHb = ubX;   // [BT_ROWS][1056] bf16 (phase 2, after GEMM5 consumed ub)

    // 1) eigenvalues
    compute_lambda<<<1, 1024, 0, stream>>>(ap, lam);

    // 2) W1 = T1 @ B_w   (fp32)
    gen_T<<<(K2 * DMODEL) / 256, 256, 0, stream>>>(T, 0);
    {
        dim3 g((K2 + 63) / 64, (DMODEL + 63) / 64);
        gemm_f32<false><<<g, 256, 0, stream>>>(T, Bw, W1,
            K2, DMODEL, DMODEL, DMODEL, DMODEL, DMODEL);
    }
    // 3) W2[d][k2] = C_w[d][:] . T2[k2][:]   (fp32)
    gen_T<<<(K2 * DMODEL) / 256, 256, 0, stream>>>(T, 1);
    {
        dim3 g((DMODEL + 63) / 64, (K2 + 63) / 64);
        gemm_f32<true><<<g, 256, 0, stream>>>(Cw, T, W2,
            DMODEL, K2, DMODEL, DMODEL, DMODEL, K2);
    }
    // 4) bf16 conversions
    conv_W1<<<(NPAD1 * DMODEL / 8 + 255) / 256, 256, 0, stream>>>(W1, W1b);
    conv_bf16<<<(DMODEL * K2 / 8 + 255) / 256, 256, 0, stream>>>(W2, W2b, DMODEL * K2 / 8);
    conv_bf16<<<(BT_ROWS * (DMODEL / 8) + 255) / 256, 256, 0, stream>>>(u, ub, BT_ROWS * (DMODEL / 8));

    // 5) U[bt][k2] = ub @ W1b^T   (bf16 MFMA, fp32 out)
    {
        dim3 g(BT_ROWS / 128, NPAD1 / 128);
        gemm_bf16<false><<<g, 256, 0, stream>>>(ub, W1b, UH,
            BT_ROWS, K2, DMODEL, K2, nullptr, nullptr);
    }
    // 6) scan over time: local, carry, apply(+bf16 convert)
    scan_local<<<(BATCH * NC * KF + 255) / 256, 256, 0, stream>>>(UH, lam);
    scan_carry<<<(BATCH * KF + 255) / 256, 256, 0, stream>>>(UH, lam, Ac);
    scan_apply_conv<<<(BATCH * NC * KF + 255) / 256, 256, 0, stream>>>(UH, lam, Ac, UHb);

    // 7) y = UHb @ W2b^T + D*u   (bf16 MFMA, fp32 out)
    {
        dim3 g(BT_ROWS / 128, DMODEL / 128);
        gemm_bf16<true><<<g, 256, 0, stream>>>(UHb, W2b, out,
            BT_ROWS, DMODEL, K2, DMODEL, u, Dv);
    }
}

// Round 4
// 290.174 us; speedup vs baseline: 4.3209x; 1.3492x over previous
//
#include <hip/hip_runtime.h>
#include <math.h>

// Problem constants
#define BATCH   8
#define SEQLEN  2048
#define DMODEL  1024
#define KFREQ   513        // unique half-spectrum freqs 0..512
#define KF      528        // padded freq count; 2*KF = 1056 = 33*32
#define K2      (2*KF)     // 1056: [0,KF)=real, [KF,2KF)=imag
#define NPAD1   1152       // K2 padded to multiple of 128
#define BT_ROWS (BATCH*SEQLEN)   // 16384
#define NC      32         // time chunks for parallel scan
#define TC      64         // chunk length; NC*TC == SEQLEN

static_assert(NC * TC == SEQLEN, "chunking must cover SEQLEN");

typedef __attribute__((ext_vector_type(4))) float f32x4;
typedef __attribute__((ext_vector_type(8))) short bf16x8;   // 8 bf16 in 4 VGPRs
typedef unsigned short ushort_t;

__device__ __forceinline__ ushort_t f2bf(float f) {
    union { float f; unsigned u; } v; v.f = f;
    unsigned r = v.u + 0x7FFFu + ((v.u >> 16) & 1u);   // RNE
    return (ushort_t)(r >> 16);
}

__device__ __forceinline__ void async_cp16(const void* g, void* l) {
    __builtin_amdgcn_global_load_lds(
        (const __attribute__((address_space(1))) void*)g,
        (__attribute__((address_space(3))) void*)l, 16, 0, 0);
}

// ---------------------------------------------------------------------------
// lambda_k = (1 - i w)/(1 + i w),  w = Im(FFT(a_full))[k]
// ---------------------------------------------------------------------------
__global__ __launch_bounds__(1024) void compute_lambda(const float* __restrict__ p,
                                                        float* __restrict__ lam) {
    __shared__ float stab[1024];
    const int tid = threadIdx.x;
    stab[tid] = sinf((float)tid * (6.28318530717958647692f / 1024.0f));
    __syncthreads();
    if (tid < KF) {
        if (tid < KFREQ) {
            float om = 0.0f;
            for (int j = 1; j <= 511; ++j)
                om = fmaf(p[j - 1], stab[(j * tid) & 1023], om);
            om *= -2.0f;
            const float w2 = om * om;
            const float den = 1.0f + w2;
            lam[tid]      = (1.0f - w2) / den;
            lam[KF + tid] = -2.0f * om / den;
        } else {
            lam[tid] = 0.0f;
            lam[KF + tid] = 0.0f;
        }
    }
}

// ---------------------------------------------------------------------------
// Trig matrix directly in bf16, [NPAD1][1024]:
//   rows [0,513):      cos(2pi kf n/1024) * scale
//   rows [KF,KF+513):  -sin(2pi kf n/1024) * scale
//   all other rows 0 (pad).
// mode 0: scale=1;  mode 1: scale = w/1024, w = (kf==0||kf==512)?1:2.
// sin table in LDS; cos(x) = sin(x + 2pi*256/1024).
// ---------------------------------------------------------------------------
__global__ __launch_bounds__(256) void gen_Tb(ushort_t* __restrict__ T, int mode) {
    __shared__ float stab[1024];
    for (int j = threadIdx.x; j < 1024; j += 256)
        stab[j] = sinf((float)j * (6.28318530717958647692f / 1024.0f));
    __syncthreads();

    const int i = blockIdx.x * 256 + threadIdx.x;   // 8 elements per thread
    if (i >= NPAD1 * DMODEL / 8) return;
    const int row = i >> 7;              // (i*8)/1024
    const int nb  = (i & 127) << 3;      // starting col

    ushort_t o[8] = {0, 0, 0, 0, 0, 0, 0, 0};
    const bool re = (row < KFREQ);
    const bool im = (row >= KF && row < KF + KFREQ);
    if (re || im) {
        const int kf = re ? row : row - KF;
        float scale = 1.0f;
        if (mode == 1) scale = ((kf == 0 || kf == 512) ? 1.0f : 2.0f) / 1024.0f;
        int m = (kf * nb) & 1023;
#pragma unroll
        for (int j = 0; j < 8; ++j) {
            const float v = im ? -stab[m] : stab[(m + 256) & 1023];
            o[j] = f2bf(v * scale);
            m = (m + kf) & 1023;
        }
    }
    reinterpret_cast<bf16x8*>(T)[i] = *reinterpret_cast<bf16x8*>(o);
}

// ---------------------------------------------------------------------------
// Transpose-convert: dst[c][r] (bf16, 1024x1024) = src[r][c] (fp32)
// ---------------------------------------------------------------------------
__global__ __launch_bounds__(256) void transp_conv(const float* __restrict__ s,
                                                   ushort_t* __restrict__ d) {
    __shared__ float tile[64][65];
    const int bx = blockIdx.x * 64;   // src col block
    const int by = blockIdx.y * 64;   // src row block
    const int lx = threadIdx.x & 63;
    const int ly = threadIdx.x >> 6;  // 0..3
#pragma unroll
    for (int i = 0; i < 16; ++i) {
        const int r = ly + i * 4;
        tile[r][lx] = s[(size_t)(by + r) * DMODEL + bx + lx];
    }
    __syncthreads();
#pragma unroll
    for (int i = 0; i < 16; ++i) {
        const int r = ly + i * 4;     // dst row-local (= src col-local)
        d[(size_t)(bx + r) * DMODEL + by + lx] = f2bf(tile[lx][r]);
    }
}

// ---------------------------------------------------------------------------
// bf16 MFMA GEMM (m97 structure): C[M][ldc] = A[M][K](bf16) @ B[Nrows][K]^T
// 128x128 tile, BK=32, 4 waves, 16x16x32 MFMA, global_load_lds staging.
// EPI:   C += Dv[n]*uu[m*DMODEL+n]  (fp32 out only)
// OUTBF: store bf16 instead of fp32
// ---------------------------------------------------------------------------
template <bool EPI, bool OUTBF>
__global__ __launch_bounds__(256) void gemm_bf16(const ushort_t* __restrict__ A,
                                                 const ushort_t* __restrict__ B,
                                                 void* __restrict__ Cv,
                                                 int M, int Nact, int K, int ldc,
                                                 const float* __restrict__ uu,
                                                 const float* __restrict__ Dv) {
    __shared__ ushort_t As[128 * 32];
    __shared__ ushort_t Bs[128 * 32];
    const int tid  = threadIdx.x;
    const int lane = tid & 63;
    const int w    = tid >> 6;
    const int m0 = blockIdx.x * 128;
    const int n0 = blockIdx.y * 128;
    const int wr = (w >> 1) * 64;
    const int wc = (w & 1) * 64;

    f32x4 acc[4][4] = {};

    const int pos  = w * 512 + lane * 8;
    const int srow = pos >> 5;           // 0..63
    const int scol = pos & 31;

    const int lr = lane & 15;
    const int lk = (lane >> 4) * 8;

    for (int k0 = 0; k0 < K; k0 += 32) {
        __syncthreads();
        async_cp16(A + (size_t)(m0 + srow)      * K + k0 + scol, As + w * 512);
        async_cp16(A + (size_t)(m0 + srow + 64) * K + k0 + scol, As + 2048 + w * 512);
        async_cp16(B + (size_t)(n0 + srow)      * K + k0 + scol, Bs + w * 512);
        async_cp16(B + (size_t)(n0 + srow + 64) * K + k0 + scol, Bs + 2048 + w * 512);
        __syncthreads();

        bf16x8 fa[4], fb[4];
#pragma unroll
        for (int mi = 0; mi < 4; ++mi)
            fa[mi] = *reinterpret_cast<const bf16x8*>(&As[(wr + mi * 16 + lr) * 32 + lk]);
#pragma unroll
        for (int ni = 0; ni < 4; ++ni)
            fb[ni] = *reinterpret_cast<const bf16x8*>(&Bs[(wc + ni * 16 + lr) * 32 + lk]);
#pragma unroll
        for (int mi = 0; mi < 4; ++mi)
#pragma unroll
            for (int ni = 0; ni < 4; ++ni)
                acc[mi][ni] = __builtin_amdgcn_mfma_f32_16x16x32_bf16(
                    fa[mi], fb[ni], acc[mi][ni], 0, 0, 0);
    }

    const int rbase = (lane >> 4) * 4;
#pragma unroll
    for (int mi = 0; mi < 4; ++mi) {
#pragma unroll
        for (int ni = 0; ni < 4; ++ni) {
            const int col = n0 + wc + ni * 16 + lr;
            if (col >= Nact) continue;
#pragma unroll
            for (int j = 0; j < 4; ++j) {
                const int row = m0 + wr + mi * 16 + rbase + j;
                float v = acc[mi][ni][j];
                if (EPI) v = fmaf(Dv[col], uu[(size_t)row * DMODEL + col], v);
                if (OUTBF)
                    ((ushort_t*)Cv)[(size_t)row * ldc + col] = f2bf(v);
                else
                    ((float*)Cv)[(size_t)row * ldc + col] = v;
            }
        }
    }
}

// ---------------------------------------------------------------------------
// fp32 -> bf16 (flat, 8 elements/thread)
// ---------------------------------------------------------------------------
__global__ __launch_bounds__(256) void conv_bf16(const float* __restrict__ s,
                                                 ushort_t* __restrict__ d, int n8) {
    const int i = blockIdx.x * 256 + threadIdx.x;
    if (i >= n8) return;
    const float4 a = reinterpret_cast<const float4*>(s)[2 * i];
    const float4 b = reinterpret_cast<const float4*>(s)[2 * i + 1];
    ushort_t o[8] = {f2bf(a.x), f2bf(a.y), f2bf(a.z), f2bf(a.w),
                     f2bf(b.x), f2bf(b.y), f2bf(b.z), f2bf(b.w)};
    reinterpret_cast<bf16x8*>(d)[i] = *reinterpret_cast<bf16x8*>(o);
}

// ---------------------------------------------------------------------------
// Chunked parallel scan (fp32, in place on UH [bt][K2])
// ---------------------------------------------------------------------------
__global__ __launch_bounds__(256) void scan_local(float* __restrict__ UH,
                                                  const float* __restrict__ lam) {
    const int gid = blockIdx.x * 256 + threadIdx.x;
    if (gid >= BATCH * NC * KF) return;
    const int kf = gid % KF;
    const int bc = gid / KF;
    const int c = bc % NC;
    const int b = bc / NC;
    const float lr = lam[kf], li = lam[KF + kf];
    float* base = UH + ((size_t)(b * SEQLEN + c * TC)) * K2 + kf;
    float hr = 0.0f, hi = 0.0f;
    for (int t = 0; t < TC; ++t) {
        const float ur = base[(size_t)t * K2];
        const float ui = base[(size_t)t * K2 + KF];
        const float nr = fmaf(lr, hr, fmaf(-li, hi, ur));
        const float ni = fmaf(lr, hi, fmaf(li, hr, ui));
        base[(size_t)t * K2] = nr;
        base[(size_t)t * K2 + KF] = ni;
        hr = nr; hi = ni;
    }
}

__global__ __launch_bounds__(256) void scan_carry(const float* __restrict__ UH,
                                                  const float* __restrict__ lam,
                                                  float* __restrict__ Ac) {
    const int gid = blockIdx.x * 256 + threadIdx.x;
    if (gid >= BATCH * KF) return;
    const int kf = gid % KF;
    const int b = gid / KF;
    const float lr = lam[kf], li = lam[KF + kf];
    float pr = lr, pi = li;          // lambda^64 via 6 squarings
    for (int s = 0; s < 6; ++s) {
        const float nr = pr * pr - pi * pi;
        const float ni = 2.0f * pr * pi;
        pr = nr; pi = ni;
    }
    float er = 0.0f, ei = 0.0f;
    for (int c = 0; c < NC; ++c) {
        const size_t ai = (size_t)(b * NC + c) * KF + kf;
        Ac[ai] = er;
        Ac[(size_t)BATCH * NC * KF + ai] = ei;
        const size_t gi = ((size_t)(b * SEQLEN + c * TC + TC - 1)) * K2 + kf;
        const float gr = UH[gi];
        const float gm = UH[gi + KF];
        const float nr = fmaf(pr, er, fmaf(-pi, ei, gr));
        const float ni = fmaf(pr, ei, fmaf(pi, er, gm));
        er = nr; ei = ni;
    }
}

// apply carries AND emit bf16 copy of H (UHb) for the output GEMM
__global__ __launch_bounds__(256) void scan_apply_conv(const float* __restrict__ UH,
                                                       const float* __restrict__ lam,
                                                       const float* __restrict__ Ac,
                                                       ushort_t* __restrict__ UHb) {
    const int gid = blockIdx.x * 256 + threadIdx.x;
    if (gid >= BATCH * NC * KF) return;
    const int kf = gid % KF;
    const int bc = gid / KF;
    const int c = bc % NC;
    const int b = bc / NC;
    const float er = Ac[gid];                                  // 0 for c==0
    const float ei = Ac[(size_t)BATCH * NC * KF + gid];
    const float lr = lam[kf], li = lam[KF + kf];
    const size_t off = ((size_t)(b * SEQLEN + c * TC)) * K2 + kf;
    const float* base = UH + off;
    ushort_t* dst = UHb + off;
    float pr = lr, pi = li;   // lambda^1
    for (int t = 0; t < TC; ++t) {
        const float hr = base[(size_t)t * K2];
        const float hi = base[(size_t)t * K2 + KF];
        const float gr = fmaf(pr, er, fmaf(-pi, ei, hr));
        const float gi = fmaf(pr, ei, fmaf(pi, er, hi));
        dst[(size_t)t * K2]      = f2bf(gr);
        dst[(size_t)t * K2 + KF] = f2bf(gi);
        const float nr = fmaf(pr, lr, -pi * li);
        const float ni = fmaf(pr, li, pi * lr);
        pr = nr; pi = ni;
    }
}

// ---------------------------------------------------------------------------
extern "C" void kernel_launch(void* const* d_in, const int* in_sizes, int n_in,
                              void* d_out, int out_size, void* d_ws, size_t ws_size,
                              hipStream_t stream) {
    const float* u  = (const float*)d_in[0];  // [B][S][D]
    const float* ap = (const float*)d_in[1];  // [512]
    const float* Bw = (const float*)d_in[2];  // [N][D]
    const float* Cw = (const float*)d_in[3];  // [D][N]
    const float* Dv = (const float*)d_in[4];  // [D]
    float* out = (float*)d_out;               // [B][S][D]

    char* ws = (char*)d_ws;
    size_t off = 0;
    auto carve = [&](size_t bytes) { char* p = ws + off; off += (bytes + 255) & ~(size_t)255; return p; };

    float*    UH   = (float*)   carve((size_t)BT_ROWS * K2 * sizeof(float));     // 69.2 MB
    ushort_t* ubX  = (ushort_t*)carve((size_t)BT_ROWS * K2 * sizeof(ushort_t));  // 34.6 MB
    ushort_t* T1b  = (ushort_t*)carve((size_t)NPAD1 * DMODEL * sizeof(ushort_t));
    ushort_t* T2b  = (ushort_t*)carve((size_t)NPAD1 * DMODEL * sizeof(ushort_t));
    ushort_t* BwTb = (ushort_t*)carve((size_t)DMODEL * DMODEL * sizeof(ushort_t));
    ushort_t* Cwb  = (ushort_t*)carve((size_t)DMODEL * DMODEL * sizeof(ushort_t));
    ushort_t* W1b  = (ushort_t*)carve((size_t)NPAD1 * DMODEL * sizeof(ushort_t));
    ushort_t* W2b  = (ushort_t*)carve((size_t)DMODEL * K2 * sizeof(ushort_t));
    float*    lam  = (float*)   carve(2 * KF * sizeof(float));
    float*    Ac   = (float*)   carve((size_t)2 * BATCH * NC * KF * sizeof(float));

    ushort_t* ub  = ubX;   // [BT_ROWS][1024] bf16 (phase 1)
    ushort_t* UHb = ubX;   // [BT_ROWS][1056] bf16 (phase 2, after GEMM-U consumed ub)

    // 1) eigenvalues
    compute_lambda<<<1, 1024, 0, stream>>>(ap, lam);

    // 2) trig matrices (bf16, padded to NPAD1 rows) + operand conversions
    gen_Tb<<<NPAD1 * DMODEL / 8 / 256, 256, 0, stream>>>(T1b, 0);
    gen_Tb<<<NPAD1 * DMODEL / 8 / 256, 256, 0, stream>>>(T2b, 1);
    {
        dim3 g(DMODEL / 64, DMODEL / 64);
        transp_conv<<<g, 256, 0, stream>>>(Bw, BwTb);
    }
    conv_bf16<<<DMODEL * DMODEL / 8 / 256, 256, 0, stream>>>(Cw, Cwb, DMODEL * DMODEL / 8);

    // 3) W1b[k2][d] = T1b @ BwTb^T   (MFMA, bf16 out; pad rows of T1b are 0)
    {
        dim3 g(NPAD1 / 128, DMODEL / 128);
        gemm_bf16<false, true><<<g, 256, 0, stream>>>(T1b, BwTb, W1b,
            NPAD1, DMODEL, DMODEL, DMODEL, nullptr, nullptr);
    }
    // 4) W2b[d][k2] = Cwb @ T2b^T   (MFMA, bf16 out)
    {
        dim3 g(DMODEL / 128, NPAD1 / 128);
        gemm_bf16<false, true><<<g, 256, 0, stream>>>(Cwb, T2b, W2b,
            DMODEL, K2, DMODEL, K2, nullptr, nullptr);
    }

    // 5) u -> bf16
    conv_bf16<<<BT_ROWS * (DMODEL / 8) / 256, 256, 0, stream>>>(u, ub, BT_ROWS * (DMODEL / 8));

    // 6) U[bt][k2] = ub @ W1b^T   (MFMA, fp32 out)
    {
        dim3 g(BT_ROWS / 128, NPAD1 / 128);
        gemm_bf16<false, false><<<g, 256, 0, stream>>>(ub, W1b, UH,
            BT_ROWS, K2, DMODEL, K2, nullptr, nullptr);
    }

    // 7) scan over time: local, carry, apply(+bf16 convert)
    scan_local<<<(BATCH * NC * KF + 255) / 256, 256, 0, stream>>>(UH, lam);
    scan_carry<<<(BATCH * KF + 255) / 256, 256, 0, stream>>>(UH, lam, Ac);
    scan_apply_conv<<<(BATCH * NC * KF + 255) / 256, 256, 0, stream>>>(UH, lam, Ac, UHb);

    // 8) y = UHb @ W2b^T + D*u   (MFMA, fp32 out)
    {
        dim3 g(BT_ROWS / 128, DMODEL / 128);
        gemm_bf16<true, false><<<g, 256, 0, stream>>>(UHb, W2b, out,
            BT_ROWS, DMODEL, K2, DMODEL, u, Dv);
    }
}